// Round 1
// 456.020 us; speedup vs baseline: 1.0508x; 1.0508x over previous
//
#include <hip/hip_runtime.h>

// ---------------------------------------------------------------------------
// CausalAttention: B=8, S=2048, D=1024, fp32 in, fp32 out.
// Round 6: shared GEMM core upgraded:
//   - double-buffered LDS (64KB) + prefetch-next-tile + counted s_waitcnt
//     vmcnt(8) + raw s_barrier (T3-minimum pipeline; loads in flight across
//     the MFMA phase instead of the __syncthreads vmcnt(0) drain)
//   - T2 XOR bank-conflict swizzle, both-sides form (rule 21): linear glds
//     dest + inverse-swizzled GLOBAL source + swizzled fragment read.
//     Kills the 16-way conflict (row stride 128B == 32 banks).
//   - T5 setprio(1) around the MFMA cluster
//   - T1 bijective XCD-aware block swizzle (all per-z grids % 8 == 0)
//   ws: Q 32 | K 32 | Vt 32 | Sc 64  (xh@Sc+0 32MB, Wh@Sc+32MB 6MB)
// ---------------------------------------------------------------------------

typedef _Float16 v8h __attribute__((ext_vector_type(8)));
typedef _Float16 v4h __attribute__((ext_vector_type(4)));
typedef float    v4f __attribute__((ext_vector_type(4)));

#define TM 128
#define TN 128
#define BK 64

__device__ __forceinline__ void async16(const _Float16* g, _Float16* l) {
  // global -> LDS direct copy, 16B/lane; LDS dest = wave-uniform base,
  // HW adds lane*16.  [validated r4]
  __builtin_amdgcn_global_load_lds(
      (__attribute__((address_space(1))) void*)(void*)g,
      (__attribute__((address_space(3))) void*)l, 16, 0, 0);
}

// Stage one 128x64 f16 slab pair into LDS (linear dest). The global source
// column-chunk is XOR-swizzled with (row&7) so that the LINEAR LDS image is
// the swizzled layout (both-sides-or-neither, rule 21). 8 glds / thread.
__device__ __forceinline__ void stage_tile(const _Float16* Ag, int lda,
                                           const _Float16* Bg, int ldb,
                                           _Float16* As, _Float16* Bs,
                                           int w, int lane) {
#pragma unroll
  for (int r = 0; r < 4; ++r) {
    const int c = w * 256 + r * 64 + lane;       // chunk id: 8 f16 elems
    const int row = c >> 3;
    const int sc = (c & 7) ^ (row & 7);          // inverse-swizzled source col
    async16(Ag + (size_t)row * lda + sc * 8, As + (w * 256 + r * 64) * 8);
    async16(Bg + (size_t)row * ldb + sc * 8, Bs + (w * 256 + r * 64) * 8);
  }
}

// MFMA core over one 128x64 LDS slab pair. A-frag lane: A[m=lane&15][k=quad*8+j].
// Reads apply the same XOR swizzle: chunk col (ks*4+quad) ^ (row&7) -> lanes
// lr=0..7 hit 8 distinct bank groups, lr=8..15 repeat = free 2-way.
__device__ __forceinline__ void mfma_slab(const _Float16* As, const _Float16* Bs,
                                          int wr, int wc, int lr, int quad,
                                          v4f acc[4][4]) {
#pragma unroll
  for (int ks = 0; ks < 2; ++ks) {
    v8h a[4], b[4];
#pragma unroll
    for (int i = 0; i < 4; ++i) {
      const int ra = wr + i * 16 + lr;
      const int rb = wc + i * 16 + lr;
      a[i] = *(const v8h*)&As[ra * BK + (((ks * 4 + quad) ^ (ra & 7)) * 8)];
      b[i] = *(const v8h*)&Bs[rb * BK + (((ks * 4 + quad) ^ (rb & 7)) * 8)];
    }
#pragma unroll
    for (int i = 0; i < 4; ++i)
#pragma unroll
      for (int j = 0; j < 4; ++j)
        acc[i][j] = __builtin_amdgcn_mfma_f32_16x16x32_f16(a[i], b[j],
                                                           acc[i][j], 0, 0, 0);
  }
}

// One pipelined K-step: prefetch tile kt+1 into buf^1, wait only for buf's
// 8 loads (counted vmcnt), raw barrier, MFMA, raw barrier (WAR protection
// for buf^1 which iter kt+1 overwrites... i.e. all waves done reading).
#define PIPE_STEP(STAGE_NEXT, HAVE_NEXT)                                     \
  do {                                                                       \
    if (HAVE_NEXT) {                                                         \
      STAGE_NEXT;                                                            \
      asm volatile("s_waitcnt vmcnt(8)" ::: "memory");                       \
    } else {                                                                 \
      asm volatile("s_waitcnt vmcnt(0)" ::: "memory");                       \
    }                                                                        \
    __builtin_amdgcn_s_barrier();                                            \
    __builtin_amdgcn_sched_barrier(0);                                       \
    __builtin_amdgcn_s_setprio(1);                                           \
    mfma_slab(As[cur], Bs[cur], wr, wc, lr, quad, acc);                      \
    __builtin_amdgcn_s_setprio(0);                                           \
    __builtin_amdgcn_sched_barrier(0);                                       \
    __builtin_amdgcn_s_barrier();                                            \
  } while (0)

// Bijective XCD-aware swizzle of the per-z 2D grid (requires nwg%8==0:
// proj 3072, scores 256, pv 128 — all divisible).
__device__ __forceinline__ void grid_swz(int& bx, int& by) {
  const int gx = gridDim.x;
  const int n = gx * gridDim.y;
  const int f = blockIdx.x + blockIdx.y * gx;
  const int s = (f & 7) * (n >> 3) + (f >> 3);
  bx = s % gx;
  by = s / gx;
}

// ---------------------------------------------------------------------------
// fp32 -> fp16, 8 elems/thread.
// ---------------------------------------------------------------------------
__global__ __launch_bounds__(256)
void cvt_f16(const float* __restrict__ src, _Float16* __restrict__ dst) {
  const int i = (blockIdx.x * 256 + threadIdx.x) * 8;
  float4 a = *(const float4*)(src + i);
  float4 b = *(const float4*)(src + i + 4);
  v8h o = {(_Float16)a.x, (_Float16)a.y, (_Float16)a.z, (_Float16)a.w,
           (_Float16)b.x, (_Float16)b.y, (_Float16)b.z, (_Float16)b.w};
  *(v8h*)(dst + i) = o;
}

// ---------------------------------------------------------------------------
// Projection: C[m][n] = X[m][:] . W[n][:], n in [0,3072) packed Q|K|V.
// Q,K stored [16384][1024]; V transposed Vt[b][d][s].
// ---------------------------------------------------------------------------
__global__ __launch_bounds__(256)
void proj_gemm(const _Float16* __restrict__ X, const _Float16* __restrict__ W,
               _Float16* __restrict__ Qb, _Float16* __restrict__ Kb,
               _Float16* __restrict__ Vt) {
  const int tid = threadIdx.x;
  int bx, by;
  grid_swz(bx, by);
  const int n0 = bx * TN, m0 = by * TM;
  const int which = n0 >> 10;                    // 0=Q 1=K 2=V, block-uniform
  const int nw = n0 & 1023;

  __shared__ _Float16 As[2][TM * BK];
  __shared__ _Float16 Bs[2][TN * BK];

  const int lane = tid & 63, w = tid >> 6;
  const int wr = (w >> 1) * 64, wc = (w & 1) * 64;
  const int lr = lane & 15, quad = lane >> 4;

  v4f acc[4][4];
#pragma unroll
  for (int i = 0; i < 4; ++i)
#pragma unroll
    for (int j = 0; j < 4; ++j) acc[i][j] = (v4f){0.f, 0.f, 0.f, 0.f};

  const _Float16* Ab = X + (size_t)m0 * 1024;
  const _Float16* Bb = W + (size_t)n0 * 1024;
  const int NK = 1024 / BK;

  stage_tile(Ab, 1024, Bb, 1024, As[0], Bs[0], w, lane);
  for (int kt = 0; kt < NK; ++kt) {
    const int cur = kt & 1;
    PIPE_STEP(stage_tile(Ab + (kt + 1) * BK, 1024, Bb + (kt + 1) * BK, 1024,
                         As[cur ^ 1], Bs[cur ^ 1], w, lane),
              kt + 1 < NK);
  }

  // C/D layout: col = lane&15, row = quad*4 + reg  [validated r4]
#pragma unroll
  for (int i = 0; i < 4; ++i) {
    const int r0 = m0 + wr + i * 16 + quad * 4;
#pragma unroll
    for (int j = 0; j < 4; ++j) {
      const int cl = wc + j * 16 + lr;
      if (which < 2) {
        _Float16* dst = (which == 0) ? Qb : Kb;
        const int col = nw + cl;
#pragma unroll
        for (int rg = 0; rg < 4; ++rg)
          dst[(size_t)(r0 + rg) * 1024 + col] = (_Float16)acc[i][j][rg];
      } else {
        const int d = nw + cl;
        const int b = r0 >> 11, s = r0 & 2047;   // 4 rows stay in-batch
        v4h o = {(_Float16)acc[i][j][0], (_Float16)acc[i][j][1],
                 (_Float16)acc[i][j][2], (_Float16)acc[i][j][3]};
        *(v4h*)(Vt + (size_t)b * 1024 * 2048 + (size_t)d * 2048 + s) = o;
      }
    }
  }
}

// ---------------------------------------------------------------------------
// Scores: Sc[b][q][k] = Q[b][q][:].K[b][k][:] (f16 raw), -inf where k > q.
// ---------------------------------------------------------------------------
__global__ __launch_bounds__(256)
void scores_gemm(const _Float16* __restrict__ Q, const _Float16* __restrict__ K,
                 _Float16* __restrict__ Sc) {
  const int tid = threadIdx.x;
  int bx, by;
  grid_swz(bx, by);
  const int bz = blockIdx.z;
  const int n0 = bx * TN, m0 = by * TM;
  _Float16* Cb = Sc + (size_t)bz * 2048 * 2048;

  if (bx > by) {                                 // fully masked tile
    const _Float16 ninf = (_Float16)(-__builtin_inff());
    v8h mv = {ninf, ninf, ninf, ninf, ninf, ninf, ninf, ninf};
#pragma unroll
    for (int it = 0; it < 8; ++it) {
      int ch = it * 256 + tid;
      int r = ch >> 4, cc = (ch & 15) * 8;
      *(v8h*)(Cb + (size_t)(m0 + r) * 2048 + n0 + cc) = mv;
    }
    return;
  }

  __shared__ _Float16 As[2][TM * BK];
  __shared__ _Float16 Bs[2][TN * BK];
  const _Float16* Qb = Q + (size_t)bz * 2048 * 1024;
  const _Float16* Kb = K + (size_t)bz * 2048 * 1024;

  const int lane = tid & 63, w = tid >> 6;
  const int wr = (w >> 1) * 64, wc = (w & 1) * 64;
  const int lr = lane & 15, quad = lane >> 4;

  v4f acc[4][4];
#pragma unroll
  for (int i = 0; i < 4; ++i)
#pragma unroll
    for (int j = 0; j < 4; ++j) acc[i][j] = (v4f){0.f, 0.f, 0.f, 0.f};

  const _Float16* Ab = Qb + (size_t)m0 * 1024;
  const _Float16* Bb = Kb + (size_t)n0 * 1024;
  const int NK = 1024 / BK;

  stage_tile(Ab, 1024, Bb, 1024, As[0], Bs[0], w, lane);
  for (int kt = 0; kt < NK; ++kt) {
    const int cur = kt & 1;
    PIPE_STEP(stage_tile(Ab + (kt + 1) * BK, 1024, Bb + (kt + 1) * BK, 1024,
                         As[cur ^ 1], Bs[cur ^ 1], w, lane),
              kt + 1 < NK);
  }

  const _Float16 ninf = (_Float16)(-__builtin_inff());
#pragma unroll
  for (int i = 0; i < 4; ++i) {
    const int r0 = m0 + wr + i * 16 + quad * 4;
#pragma unroll
    for (int j = 0; j < 4; ++j) {
      const int cc = n0 + wc + j * 16 + lr;
#pragma unroll
      for (int rg = 0; rg < 4; ++rg) {
        const int rr = r0 + rg;
        Cb[(size_t)rr * 2048 + cc] = (cc > rr) ? ninf : (_Float16)acc[i][j][rg];
      }
    }
  }
}

// ---------------------------------------------------------------------------
// Row softmax in place (f16), scale 1/32 inside exp.
// ---------------------------------------------------------------------------
__global__ __launch_bounds__(256)
void softmax_rows(_Float16* __restrict__ Sc) {
  _Float16* base = Sc + (size_t)blockIdx.x * 2048;
  const int tid = threadIdx.x;
  const int lane = tid & 63, w = tid >> 6;

  v8h pv = *(const v8h*)(base + tid * 8);
  float f[8];
#pragma unroll
  for (int j = 0; j < 8; ++j) f[j] = (float)pv[j];

  float mx = f[0];
#pragma unroll
  for (int j = 1; j < 8; ++j) mx = fmaxf(mx, f[j]);
#pragma unroll
  for (int off = 32; off; off >>= 1) mx = fmaxf(mx, __shfl_xor(mx, off));
  __shared__ float redm[4], reds[4];
  if (lane == 0) redm[w] = mx;
  __syncthreads();
  mx = fmaxf(fmaxf(redm[0], redm[1]), fmaxf(redm[2], redm[3]));

  const float scale = 0.03125f;                  // 1/sqrt(1024)
  float e[8], s = 0.f;
#pragma unroll
  for (int j = 0; j < 8; ++j) {
    e[j] = __expf((f[j] - mx) * scale);
    s += e[j];
  }
#pragma unroll
  for (int off = 32; off; off >>= 1) s += __shfl_xor(s, off);
  if (lane == 0) reds[w] = s;
  __syncthreads();
  s = reds[0] + reds[1] + reds[2] + reds[3];
  const float inv = 1.0f / s;
#pragma unroll
  for (int j = 0; j < 8; ++j) pv[j] = (_Float16)(e[j] * inv);
  *(v8h*)(base + tid * 8) = pv;
}

// ---------------------------------------------------------------------------
// Out (fp32): out[b][q][d] = sum_k P[b][q][k] * Vt[b][d][k]; K-loop causally
// truncated to (by+1)*128.
// ---------------------------------------------------------------------------
__global__ __launch_bounds__(256)
void pv_gemm(const _Float16* __restrict__ P, const _Float16* __restrict__ Vt,
             float* __restrict__ Out) {
  const int tid = threadIdx.x;
  int bx, by;
  grid_swz(bx, by);
  const int bz = blockIdx.z;
  const int n0 = bx * TN, m0 = by * TM;
  const _Float16* Pb = P + (size_t)bz * 2048 * 2048;
  const _Float16* Vb = Vt + (size_t)bz * 1024 * 2048;
  float* Cb = Out + (size_t)bz * 2048 * 1024;

  __shared__ _Float16 As[2][TM * BK];
  __shared__ _Float16 Bs[2][TN * BK];

  const int lane = tid & 63, w = tid >> 6;
  const int wr = (w >> 1) * 64, wc = (w & 1) * 64;
  const int lr = lane & 15, quad = lane >> 4;

  v4f acc[4][4];
#pragma unroll
  for (int i = 0; i < 4; ++i)
#pragma unroll
    for (int j = 0; j < 4; ++j) acc[i][j] = (v4f){0.f, 0.f, 0.f, 0.f};

  const _Float16* Ab = Pb + (size_t)m0 * 2048;
  const _Float16* Bb = Vb + (size_t)n0 * 2048;
  const int NK = (by + 1) * 2;                   // cover k < (by+1)*128

  stage_tile(Ab, 2048, Bb, 2048, As[0], Bs[0], w, lane);
  for (int kt = 0; kt < NK; ++kt) {
    const int cur = kt & 1;
    PIPE_STEP(stage_tile(Ab + (kt + 1) * BK, 2048, Bb + (kt + 1) * BK, 2048,
                         As[cur ^ 1], Bs[cur ^ 1], w, lane),
              kt + 1 < NK);
  }

#pragma unroll
  for (int i = 0; i < 4; ++i) {
    const int r0 = m0 + wr + i * 16 + quad * 4;
#pragma unroll
    for (int j = 0; j < 4; ++j) {
      const int cc = n0 + wc + j * 16 + lr;
#pragma unroll
      for (int rg = 0; rg < 4; ++rg)
        Cb[(size_t)(r0 + rg) * 1024 + cc] = acc[i][j][rg];   // fp32 store
    }
  }
}

// ---------------------------------------------------------------------------
extern "C" void kernel_launch(void* const* d_in, const int* in_sizes, int n_in,
                              void* d_out, int out_size, void* d_ws, size_t ws_size,
                              hipStream_t stream) {
  const int B = 8, S = 2048, D = 1024;
  const int M = B * S;                           // 16384
  const float* x  = (const float*)d_in[0];
  const float* Wq = (const float*)d_in[1];
  const float* Wk = (const float*)d_in[2];
  const float* Wv = (const float*)d_in[3];
  float* out = (float*)d_out;

  // ws: Q 32MB | K 32MB | Vt 32MB | Sc 64MB (160 MB total, validated r4).
  // xh (32MB) and Wh (6MB) alias the head of Sc — dead before scores writes.
  char* ws = (char*)d_ws;
  _Float16* Qb = (_Float16*)ws;                          // [M][1024]
  _Float16* Kb = (_Float16*)(ws + (size_t)33554432);     // [M][1024]
  _Float16* Vt = (_Float16*)(ws + (size_t)67108864);     // [B][1024][2048]
  _Float16* Sc = (_Float16*)(ws + (size_t)100663296);    // [B][2048][2048]
  _Float16* xh = Sc;                                     // [M][1024]   (alias)
  _Float16* Wh = Sc + (size_t)M * D;                     // [3072][1024](alias)

  // 1) fp32 -> fp16 converts (memory-bound)
  cvt_f16<<<(M * D) / 2048, 256, 0, stream>>>(x, xh);
  cvt_f16<<<(D * D) / 2048, 256, 0, stream>>>(Wq, Wh);
  cvt_f16<<<(D * D) / 2048, 256, 0, stream>>>(Wk, Wh + (size_t)D * D);
  cvt_f16<<<(D * D) / 2048, 256, 0, stream>>>(Wv, Wh + (size_t)2 * D * D);

  // 2) QKV projection (pipelined dbuf GEMM)
  proj_gemm<<<dim3(24, M / TM, 1), 256, 0, stream>>>(xh, Wh, Qb, Kb, Vt);

  // 3) raw scores with causal -inf mask
  scores_gemm<<<dim3(S / TN, S / TM, B), 256, 0, stream>>>(Qb, Kb, Sc);

  // 4) softmax rows in place
  softmax_rows<<<B * S, 256, 0, stream>>>(Sc);

  // 5) out = P @ Vt, fp32 store
  pv_gemm<<<dim3(D / TN, S / TM, B), 256, 0, stream>>>(Sc, Vt, out);
}